// Round 8
// baseline (172.731 us; speedup 1.0000x reference)
//
#include <hip/hip_runtime.h>
#include <hip/hip_bf16.h>

typedef __attribute__((ext_vector_type(8))) short short8;
typedef __attribute__((ext_vector_type(4))) short short4_t;
typedef __attribute__((ext_vector_type(4))) float f32x4;

#define CH 64

__device__ __forceinline__ ushort f2b(float f) {
  __hip_bfloat16 h = __float2bfloat16(f);
  return *reinterpret_cast<ushort*>(&h);
}
__device__ __forceinline__ float b2f(ushort u) {
  return __uint_as_float(((unsigned)u) << 16);
}
__device__ __forceinline__ void wave_lds_sync() {
  asm volatile("s_waitcnt lgkmcnt(0)" ::: "memory");
  __builtin_amdgcn_wave_barrier();
}

// ---------------- pre: convert+transpose W  +  edge histogram ----------------
// blocks [0,256): W convert; [256, 256+nhist): histogram (counts pre-zeroed by memset)
__global__ __launch_bounds__(256) void pre_kernel(
    const float* __restrict__ Wq, const float* __restrict__ Wk,
    const float* __restrict__ Wv, const float* __restrict__ Wo,
    ushort* __restrict__ Wt, const int* __restrict__ src,
    int* __restrict__ counts, int E) {
  __shared__ float L[32][33];
  int b = blockIdx.x;
  int t = threadIdx.x;
  if (b < 256) {
    int mat = b >> 6;
    int tile = b & 63;
    int tr = (tile >> 3) * 32;
    int tc = (tile & 7) * 32;
    const float* W = (mat == 0) ? Wq : (mat == 1) ? Wk : (mat == 2) ? Wv : Wo;
    int c = t & 31, r8 = t >> 5;
#pragma unroll
    for (int rr = 0; rr < 4; ++rr) {
      int r = r8 + rr * 8;
      L[r][c] = W[(size_t)(tr + r) * 256 + tc + c];
    }
    __syncthreads();
#pragma unroll
    for (int rr = 0; rr < 4; ++rr) {
      int cc = r8 + rr * 8;
      Wt[(size_t)(mat * 256 + tc + cc) * 256 + tr + c] = f2b(L[c][cc]);
    }
  } else {
    int e = (b - 256) * 256 + t;
    if (e < E) atomicAdd(&counts[src[e]], 1);
  }
}

// ------- fused: QKV MFMA GEMM (LDS-staged, swizzled, inline X cvt) + scan ---
// blocks [0,ngemm): gemm tiles; bid==ngemm: single-block scan (256 threads).
__global__ __launch_bounds__(256) void gemm_scan(
    const float* __restrict__ X, const ushort* __restrict__ Wt,
    ushort* __restrict__ QKVb, const int* __restrict__ counts,
    int* __restrict__ offs, int* __restrict__ cursor,
    int N, int ngemm) {
  __shared__ ushort sA[128 * 64];
  __shared__ ushort sB[128 * 64];
  __shared__ int wsum[4];
  __shared__ int wexc[4];
  __shared__ int s_total;
  int bid = blockIdx.x;
  int t = threadIdx.x;
  if (bid == ngemm) {
    // ---- scan: 256 threads, thread-serial segments ----
    int lane = t & 63, wv = t >> 6;
    int per = (N + 255) >> 8;
    int b0 = t * per;
    int e0 = min(b0 + per, N);
    int sum = 0;
    for (int i = b0; i < e0; ++i) sum += counts[i];
    int x = sum;
#pragma unroll
    for (int off = 1; off < 64; off <<= 1) {
      int y = __shfl_up(x, off);
      if (lane >= off) x += y;
    }
    if (lane == 63) wsum[wv] = x;
    __syncthreads();
    if (t == 0) {
      int run = 0;
#pragma unroll
      for (int k = 0; k < 4; ++k) { wexc[k] = run; run += wsum[k]; }
      s_total = run;
    }
    __syncthreads();
    int running = wexc[wv] + (x - sum);
    for (int i = b0; i < e0; ++i) {
      int c = counts[i];
      offs[i] = running;
      cursor[i] = running;
      running += c;
    }
    if (t == 0) offs[N] = s_total;
    return;
  }
  int bx = bid / 6, by = bid % 6;
  char* cA = (char*)sA;
  char* cB = (char*)sB;
  int lane = t & 63, w = t >> 6;
  int wr = w >> 1, wc = w & 1;
  int row0 = bx * 128;
  int lr = lane & 15, kg = lane >> 4;
  f32x4 acc[4][4] = {};
  for (int k0 = 0; k0 < 256; k0 += 64) {
#pragma unroll
    for (int it = 0; it < 4; ++it) {
      int slot = t + it * 256;
      int row = slot >> 3, kc = slot & 7;
      int grow = min(row0 + row, N - 1);
      const float* xp = X + (size_t)grow * 256 + k0 + kc * 8;
      float4 x0 = *reinterpret_cast<const float4*>(xp);
      float4 x1 = *reinterpret_cast<const float4*>(xp + 4);
      short8 va;
      va[0] = (short)f2b(x0.x); va[1] = (short)f2b(x0.y);
      va[2] = (short)f2b(x0.z); va[3] = (short)f2b(x0.w);
      va[4] = (short)f2b(x1.x); va[5] = (short)f2b(x1.y);
      va[6] = (short)f2b(x1.z); va[7] = (short)f2b(x1.w);
      *reinterpret_cast<short8*>(cA + ((row * 128 + kc * 16) ^ ((row & 7) << 4))) = va;
      short8 vb = *reinterpret_cast<const short8*>(Wt + (size_t)(by * 128 + row) * 256 + k0 + kc * 8);
      *reinterpret_cast<short8*>(cB + ((row * 128 + kc * 16) ^ ((row & 7) << 4))) = vb;
    }
    __syncthreads();
#pragma unroll
    for (int ks = 0; ks < 2; ++ks) {
      short8 af[4], bf[4];
#pragma unroll
      for (int fr = 0; fr < 4; ++fr) {
        int row = wr * 64 + fr * 16 + lr;
        af[fr] = *reinterpret_cast<const short8*>(
            cA + ((row * 128 + ks * 64 + kg * 16) ^ ((row & 7) << 4)));
      }
#pragma unroll
      for (int fc = 0; fc < 4; ++fc) {
        int col = wc * 64 + fc * 16 + lr;
        bf[fc] = *reinterpret_cast<const short8*>(
            cB + ((col * 128 + ks * 64 + kg * 16) ^ ((col & 7) << 4)));
      }
#pragma unroll
      for (int fr = 0; fr < 4; ++fr)
#pragma unroll
        for (int fc = 0; fc < 4; ++fc)
          acc[fr][fc] = __builtin_amdgcn_mfma_f32_16x16x32_bf16(af[fr], bf[fc], acc[fr][fc], 0, 0, 0);
    }
    __syncthreads();
  }
  int orow = kg * 4;
#pragma unroll
  for (int fr = 0; fr < 4; ++fr)
#pragma unroll
    for (int fc = 0; fc < 4; ++fc)
#pragma unroll
      for (int r = 0; r < 4; ++r) {
        int row = row0 + wr * 64 + fr * 16 + orow + r;
        int col = by * 128 + wc * 64 + fc * 16 + lr;
        if (row < N) QKVb[(size_t)row * 768 + col] = f2b(acc[fr][fc][r]);
      }
}

// ---------------- scatter: packed int2{tgt, w_bits} ----------------
__global__ void scatter_kernel(const int* __restrict__ src, const int* __restrict__ tgt,
                               const float* __restrict__ ew, int* __restrict__ cursor,
                               int2* __restrict__ ews, int E) {
  int e = blockIdx.x * blockDim.x + threadIdx.x;
  if (e < E) {
    int pos = atomicAdd(&cursor[src[e]], 1);
    ews[pos] = make_int2(tgt[e], __float_as_int(ew[e]));
  }
}

// ---------------- per-node attention: one WAVE per node (round-4 structure) --
// Score phase: lane (e8=l>>3, h=l&7), depth-2 K pipeline, padded loads.
// PV phase: lane owns dims l*4..l*4+3 (head l>>3), 8-edge batched loads.
__global__ __launch_bounds__(256) void attn_kernel(
    const ushort* __restrict__ QKVb,
    const int* __restrict__ offs, const int2* __restrict__ ews,
    const float* __restrict__ We, ushort* __restrict__ AGGb, int N) {
  __shared__ float s_p[4][CH][8];
  __shared__ int s_tgt[4][CH];
  __shared__ float s_w[4][CH];
  int t = threadIdx.x;
  int w = t >> 6;
  int l = t & 63;
  int i = blockIdx.x * 4 + w;
  if (i >= N) return;
  int e8 = l >> 3;
  int h = l & 7;
  int hacc = l >> 3;
  const float scale = 0.17677669529663687f;
  float we = We[h];

  float qf[32];
  {
    const short8* qr = reinterpret_cast<const short8*>(QKVb + (size_t)i * 768 + h * 32);
#pragma unroll
    for (int d = 0; d < 4; ++d) {
      short8 qv = qr[d];
#pragma unroll
      for (int x = 0; x < 8; ++x) qf[d * 8 + x] = b2f((ushort)qv[x]);
    }
  }

  float m = -1e30f, lsum = 0.f;
  float acc0 = 0.f, acc1 = 0.f, acc2 = 0.f, acc3 = 0.f;
  int beg = offs[i], end = offs[i + 1];

  for (int base = beg; base < end; base += CH) {
    int cnt = min(CH, end - base);
    int cnt_pad = (cnt + 7) & ~7;  // >= 8 always
    {
      bool valid = l < cnt;
      int2 te = valid ? ews[base + l] : make_int2(i, 0);
      s_tgt[w][l] = te.x;
      s_w[w][l] = valid ? __int_as_float(te.y) : 0.f;
    }
    wave_lds_sync();

    // ---- score phase: depth-2 pipelined sections of 8 edges ----
    float s_local[8];
#pragma unroll
    for (int it = 0; it < 8; ++it) s_local[it] = -1e30f;

    short8 kc[4], kn[4];
    {
      const short8* p = reinterpret_cast<const short8*>(
          QKVb + (size_t)s_tgt[w][e8] * 768 + 256 + h * 32);
#pragma unroll
      for (int d = 0; d < 4; ++d) kc[d] = p[d];
    }
    if (8 < cnt_pad) {
      const short8* p = reinterpret_cast<const short8*>(
          QKVb + (size_t)s_tgt[w][8 + e8] * 768 + 256 + h * 32);
#pragma unroll
      for (int d = 0; d < 4; ++d) kn[d] = p[d];
    }
    float cmax = -1e30f;
#pragma unroll
    for (int it = 0; it < 8; ++it) {
      if (it * 8 >= cnt_pad) break;  // wave-uniform
      float dot = 0.f;
#pragma unroll
      for (int d = 0; d < 4; ++d)
#pragma unroll
        for (int x = 0; x < 8; ++x)
          dot += qf[d * 8 + x] * b2f((ushort)kc[d][x]);
      int j = it * 8 + e8;
      float s = (j < cnt) ? dot * scale + s_w[w][j] * we : -1e30f;
      s_local[it] = s;
      cmax = fmaxf(cmax, s);
#pragma unroll
      for (int d = 0; d < 4; ++d) kc[d] = kn[d];
      if ((it + 2) * 8 < cnt_pad) {
        const short8* p = reinterpret_cast<const short8*>(
            QKVb + (size_t)s_tgt[w][(it + 2) * 8 + e8] * 768 + 256 + h * 32);
#pragma unroll
        for (int d = 0; d < 4; ++d) kn[d] = p[d];
      }
    }
    cmax = fmaxf(cmax, __shfl_xor(cmax, 8));
    cmax = fmaxf(cmax, __shfl_xor(cmax, 16));
    cmax = fmaxf(cmax, __shfl_xor(cmax, 32));
    float newm = fmaxf(m, cmax);
    float f = __expf(m - newm);
    float psum = 0.f;
#pragma unroll
    for (int it = 0; it < 8; ++it) {
      if (it * 8 >= cnt_pad) break;
      int j = it * 8 + e8;
      float p = __expf(s_local[it] - newm);
      s_p[w][j][h] = p;
      psum += p;
    }
    psum += __shfl_xor(psum, 8);
    psum += __shfl_xor(psum, 16);
    psum += __shfl_xor(psum, 32);
    lsum = lsum * f + psum;
    m = newm;
    float f_acc = __shfl(f, hacc);
    acc0 *= f_acc; acc1 *= f_acc; acc2 *= f_acc; acc3 *= f_acc;
    wave_lds_sync();

    // ---- PV phase: 8-edge load batches ----
#pragma unroll
    for (int g = 0; g < 8; ++g) {
      if (g * 8 >= cnt_pad) break;
      float pv[8];
      short4_t vv[8];
#pragma unroll
      for (int k = 0; k < 8; ++k) {
        int j = g * 8 + k;
        pv[k] = s_p[w][j][hacc];
        vv[k] = *reinterpret_cast<const short4_t*>(
            QKVb + (size_t)s_tgt[w][j] * 768 + 512 + l * 4);
      }
#pragma unroll
      for (int k = 0; k < 8; ++k) {
        acc0 += pv[k] * b2f((ushort)vv[k][0]);
        acc1 += pv[k] * b2f((ushort)vv[k][1]);
        acc2 += pv[k] * b2f((ushort)vv[k][2]);
        acc3 += pv[k] * b2f((ushort)vv[k][3]);
      }
    }
    wave_lds_sync();
  }
  float lsum_acc = __shfl(lsum, hacc);
  float rinv = (lsum_acc > 0.f) ? 1.f / lsum_acc : 0.f;
  short4_t o;
  o[0] = (short)f2b(acc0 * rinv);
  o[1] = (short)f2b(acc1 * rinv);
  o[2] = (short)f2b(acc2 * rinv);
  o[3] = (short)f2b(acc3 * rinv);
  *reinterpret_cast<short4_t*>(AGGb + (size_t)i * 256 + l * 4) = o;
}

// ------- output GEMM (LDS-staged, BM=64 BN=256) + residual + LayerNorm ------
__global__ __launch_bounds__(256) void out_ln(
    const ushort* __restrict__ AGGb, const ushort* __restrict__ Wot,
    const float* __restrict__ X, const float* __restrict__ g, const float* __restrict__ bb,
    float* __restrict__ out, int N) {
  __shared__ ushort sA[64 * 64];
  __shared__ ushort sB[256 * 64];
  char* cA = (char*)sA;
  char* cB = (char*)sB;
  int t = threadIdx.x;
  int lane = t & 63, w = t >> 6;
  int row0 = blockIdx.x * 64;
  int lr = lane & 15, kg = lane >> 4;
  f32x4 acc[16] = {};
  for (int k0 = 0; k0 < 256; k0 += 64) {
#pragma unroll
    for (int it = 0; it < 2; ++it) {
      int slot = t + it * 256;
      int row = slot >> 3, kc = slot & 7;
      int grow = min(row0 + row, N - 1);
      short8 va = *reinterpret_cast<const short8*>(AGGb + (size_t)grow * 256 + k0 + kc * 8);
      *reinterpret_cast<short8*>(cA + ((row * 128 + kc * 16) ^ ((row & 7) << 4))) = va;
    }
#pragma unroll
    for (int it = 0; it < 8; ++it) {
      int slot = t + it * 256;
      int col = slot >> 3, kc = slot & 7;
      short8 vb = *reinterpret_cast<const short8*>(Wot + (size_t)col * 256 + k0 + kc * 8);
      *reinterpret_cast<short8*>(cB + ((col * 128 + kc * 16) ^ ((col & 7) << 4))) = vb;
    }
    __syncthreads();
#pragma unroll
    for (int ks = 0; ks < 2; ++ks) {
      int arow = w * 16 + lr;
      short8 a = *reinterpret_cast<const short8*>(
          cA + ((arow * 128 + ks * 64 + kg * 16) ^ ((arow & 7) << 4)));
#pragma unroll
      for (int fc = 0; fc < 16; ++fc) {
        int col = fc * 16 + lr;
        short8 b = *reinterpret_cast<const short8*>(
            cB + ((col * 128 + ks * 64 + kg * 16) ^ ((col & 7) << 4)));
        acc[fc] = __builtin_amdgcn_mfma_f32_16x16x32_bf16(a, b, acc[fc], 0, 0, 0);
      }
    }
    __syncthreads();
  }
  float g16[16], b16[16];
#pragma unroll
  for (int fc = 0; fc < 16; ++fc) {
    g16[fc] = g[fc * 16 + lr];
    b16[fc] = bb[fc * 16 + lr];
  }
#pragma unroll
  for (int r = 0; r < 4; ++r) {
    int rowl = kg * 4 + r;
    int grow = row0 + w * 16 + rowl;
    int growc = min(grow, N - 1);
    float xv[16];
    float s = 0.f, ss = 0.f;
#pragma unroll
    for (int fc = 0; fc < 16; ++fc) {
      float v = acc[fc][r] + X[(size_t)growc * 256 + fc * 16 + lr];
      xv[fc] = v;
      s += v;
      ss += v * v;
    }
    s += __shfl_xor(s, 1);  ss += __shfl_xor(ss, 1);
    s += __shfl_xor(s, 2);  ss += __shfl_xor(ss, 2);
    s += __shfl_xor(s, 4);  ss += __shfl_xor(ss, 4);
    s += __shfl_xor(s, 8);  ss += __shfl_xor(ss, 8);
    float mu = s * (1.f / 256.f);
    float var = ss * (1.f / 256.f) - mu * mu;
    float rs = rsqrtf(var + 1e-5f);
    if (grow < N) {
#pragma unroll
      for (int fc = 0; fc < 16; ++fc)
        out[(size_t)grow * 256 + fc * 16 + lr] = (xv[fc] - mu) * rs * g16[fc] + b16[fc];
    }
  }
}

extern "C" void kernel_launch(void* const* d_in, const int* in_sizes, int n_in,
                              void* d_out, int out_size, void* d_ws, size_t ws_size,
                              hipStream_t stream) {
  const float* X  = (const float*)d_in[0];
  const int* eidx = (const int*)d_in[1];
  const float* ew = (const float*)d_in[2];
  const float* Wq = (const float*)d_in[3];
  const float* Wk = (const float*)d_in[4];
  const float* Wv = (const float*)d_in[5];
  const float* We = (const float*)d_in[6];
  const float* Wo = (const float*)d_in[7];
  const float* g  = (const float*)d_in[8];
  const float* b  = (const float*)d_in[9];
  int N = in_sizes[0] / 256;
  int E = in_sizes[1] / 2;
  const int* src = eidx;
  const int* tgt = eidx + E;
  float* out = (float*)d_out;

  char* w = (char*)d_ws;
  ushort* Wt   = (ushort*)w;  w += (size_t)1024 * 256 * 2;
  ushort* QKVb = (ushort*)w;  w += (size_t)N * 768 * 2;
  ushort* AGGb = (ushort*)w;  w += (size_t)N * 256 * 2;
  int* counts  = (int*)w;     w += (size_t)N * 4;
  int* offs    = (int*)w;     w += (size_t)(N + 1) * 4;
  int* cursor  = (int*)w;     w += (size_t)N * 4;
  int2* ews    = (int2*)w;    w += (size_t)E * 8;
  const ushort* Wot = Wt + (size_t)768 * 256;

  hipMemsetAsync(counts, 0, (size_t)N * 4, stream);

  int nhist = (E + 255) / 256;
  pre_kernel<<<256 + nhist, 256, 0, stream>>>(Wq, Wk, Wv, Wo, Wt, src, counts, E);

  int ngemm = ((N + 127) / 128) * 6;
  gemm_scan<<<ngemm + 1, 256, 0, stream>>>(X, Wt, QKVb, counts, offs, cursor, N, ngemm);

  scatter_kernel<<<(E + 255) / 256, 256, 0, stream>>>(src, tgt, ew, cursor, ews, E);
  attn_kernel<<<(N + 3) / 4, 256, 0, stream>>>(QKVb, offs, ews, We, AGGb, N);
  out_ln<<<(N + 63) / 64, 256, 0, stream>>>(AGGb, Wot, X, g, b, out, N);
}

// Round 9
// 160.119 us; speedup vs baseline: 1.0788x; 1.0788x over previous
//
#include <hip/hip_runtime.h>
#include <hip/hip_bf16.h>

typedef __attribute__((ext_vector_type(8))) short short8;
typedef __attribute__((ext_vector_type(4))) short short4_t;
typedef __attribute__((ext_vector_type(4))) float f32x4;

#define CH 64

__device__ __forceinline__ ushort f2b(float f) {
  __hip_bfloat16 h = __float2bfloat16(f);
  return *reinterpret_cast<ushort*>(&h);
}
__device__ __forceinline__ float b2f(ushort u) {
  return __uint_as_float(((unsigned)u) << 16);
}
__device__ __forceinline__ void wave_lds_sync() {
  asm volatile("s_waitcnt lgkmcnt(0)" ::: "memory");
  __builtin_amdgcn_wave_barrier();
}

// ---------------- pre: convert+transpose W  +  edge histogram ----------------
__global__ __launch_bounds__(256) void pre_kernel(
    const float* __restrict__ Wq, const float* __restrict__ Wk,
    const float* __restrict__ Wv, const float* __restrict__ Wo,
    ushort* __restrict__ Wt, const int* __restrict__ src,
    int* __restrict__ counts, int E) {
  __shared__ float L[32][33];
  int b = blockIdx.x;
  int t = threadIdx.x;
  if (b < 256) {
    int mat = b >> 6;
    int tile = b & 63;
    int tr = (tile >> 3) * 32;
    int tc = (tile & 7) * 32;
    const float* W = (mat == 0) ? Wq : (mat == 1) ? Wk : (mat == 2) ? Wv : Wo;
    int c = t & 31, r8 = t >> 5;
#pragma unroll
    for (int rr = 0; rr < 4; ++rr) {
      int r = r8 + rr * 8;
      L[r][c] = W[(size_t)(tr + r) * 256 + tc + c];
    }
    __syncthreads();
#pragma unroll
    for (int rr = 0; rr < 4; ++rr) {
      int cc = r8 + rr * 8;
      Wt[(size_t)(mat * 256 + tc + cc) * 256 + tr + c] = f2b(L[c][cc]);
    }
  } else {
    int e = (b - 256) * 256 + t;
    if (e < E) atomicAdd(&counts[src[e]], 1);
  }
}

// ------- QKV MFMA GEMM: LDS-staged, swizzled, XCD-chunked, reg-prefetch -----
__global__ __launch_bounds__(256) void qkv_gemm(
    const float* __restrict__ X, const ushort* __restrict__ Wt,
    ushort* __restrict__ QKVb, int N) {
  __shared__ ushort sA[128 * 64];
  __shared__ ushort sB[128 * 64];
  char* cA = (char*)sA;
  char* cB = (char*)sB;
  int t = threadIdx.x;
  // XCD-bijective swizzle (m204): contiguous wgid chunks per XCD
  int nwg = gridDim.x;
  int o = blockIdx.x;
  int q = nwg >> 3, r = nwg & 7;
  int xcd = o & 7;
  int wgid = (xcd < r ? xcd * (q + 1) : r * (q + 1) + (xcd - r) * q) + (o >> 3);
  int bx = wgid / 6, by = wgid % 6;
  int lane = t & 63, w = t >> 6;
  int wr = w >> 1, wc = w & 1;
  int row0 = bx * 128;
  int lr = lane & 15, kg = lane >> 4;

  // per-thread staging slots
  int slotrow[4], slotkc[4], growv[4];
#pragma unroll
  for (int it = 0; it < 4; ++it) {
    int slot = t + it * 256;
    slotrow[it] = slot >> 3;
    slotkc[it] = slot & 7;
    growv[it] = min(row0 + slotrow[it], N - 1);
  }

  float4 px0[4], px1[4];
  short8 pwb[4];
#define ISSUE(K0)                                                                 \
  {                                                                               \
    _Pragma("unroll") for (int it = 0; it < 4; ++it) {                            \
      const float* xp = X + (size_t)growv[it] * 256 + (K0) + slotkc[it] * 8;      \
      px0[it] = *reinterpret_cast<const float4*>(xp);                             \
      px1[it] = *reinterpret_cast<const float4*>(xp + 4);                         \
      pwb[it] = *reinterpret_cast<const short8*>(                                 \
          Wt + (size_t)(by * 128 + slotrow[it]) * 256 + (K0) + slotkc[it] * 8);   \
    }                                                                             \
  }

  f32x4 acc[4][4] = {};
  ISSUE(0);
#pragma unroll
  for (int k0 = 0; k0 < 256; k0 += 64) {
    // write staged regs -> LDS (swizzled)
#pragma unroll
    for (int it = 0; it < 4; ++it) {
      short8 va;
      va[0] = (short)f2b(px0[it].x); va[1] = (short)f2b(px0[it].y);
      va[2] = (short)f2b(px0[it].z); va[3] = (short)f2b(px0[it].w);
      va[4] = (short)f2b(px1[it].x); va[5] = (short)f2b(px1[it].y);
      va[6] = (short)f2b(px1[it].z); va[7] = (short)f2b(px1[it].w);
      int row = slotrow[it], kc = slotkc[it];
      *reinterpret_cast<short8*>(cA + ((row * 128 + kc * 16) ^ ((row & 7) << 4))) = va;
      *reinterpret_cast<short8*>(cB + ((row * 128 + kc * 16) ^ ((row & 7) << 4))) = pwb[it];
    }
    __syncthreads();
    if (k0 < 192) ISSUE(k0 + 64);  // overlap next-tile loads with MFMA
#pragma unroll
    for (int ks = 0; ks < 2; ++ks) {
      short8 af[4], bf[4];
#pragma unroll
      for (int fr = 0; fr < 4; ++fr) {
        int row = wr * 64 + fr * 16 + lr;
        af[fr] = *reinterpret_cast<const short8*>(
            cA + ((row * 128 + ks * 64 + kg * 16) ^ ((row & 7) << 4)));
      }
#pragma unroll
      for (int fc = 0; fc < 4; ++fc) {
        int col = wc * 64 + fc * 16 + lr;
        bf[fc] = *reinterpret_cast<const short8*>(
            cB + ((col * 128 + ks * 64 + kg * 16) ^ ((col & 7) << 4)));
      }
#pragma unroll
      for (int fr = 0; fr < 4; ++fr)
#pragma unroll
        for (int fc = 0; fc < 4; ++fc)
          acc[fr][fc] = __builtin_amdgcn_mfma_f32_16x16x32_bf16(af[fr], bf[fc], acc[fr][fc], 0, 0, 0);
    }
    __syncthreads();
  }
#undef ISSUE
  int orow = kg * 4;
#pragma unroll
  for (int fr = 0; fr < 4; ++fr)
#pragma unroll
    for (int fc = 0; fc < 4; ++fc)
#pragma unroll
      for (int r2 = 0; r2 < 4; ++r2) {
        int row = row0 + wr * 64 + fr * 16 + orow + r2;
        int col = by * 128 + wc * 64 + fc * 16 + lr;
        if (row < N) QKVb[(size_t)row * 768 + col] = f2b(acc[fr][fc][r2]);
      }
}

// ---------------- scan: single block, 1024 threads, thread-serial segments ---
__global__ __launch_bounds__(1024) void scan_kernel(
    const int* __restrict__ counts, int* __restrict__ offs, int* __restrict__ cursor, int N) {
  __shared__ int wsum[16];
  __shared__ int wexc[16];
  __shared__ int s_total;
  int t = threadIdx.x;
  int lane = t & 63, wv = t >> 6;
  int per = (N + 1023) >> 10;
  int b0 = t * per;
  int e0 = min(b0 + per, N);
  int sum = 0;
  for (int i = b0; i < e0; ++i) sum += counts[i];
  int x = sum;
#pragma unroll
  for (int off = 1; off < 64; off <<= 1) {
    int y = __shfl_up(x, off);
    if (lane >= off) x += y;
  }
  if (lane == 63) wsum[wv] = x;
  __syncthreads();
  if (t < 64) {
    int s = (lane < 16) ? wsum[lane] : 0;
    int xs = s;
#pragma unroll
    for (int off = 1; off < 16; off <<= 1) {
      int y = __shfl_up(xs, off);
      if (lane >= off) xs += y;
    }
    if (lane < 16) wexc[lane] = xs - s;
    if (lane == 15) s_total = xs;
  }
  __syncthreads();
  int running = wexc[wv] + (x - sum);
  for (int i = b0; i < e0; ++i) {
    int c = counts[i];
    offs[i] = running;
    cursor[i] = running;
    running += c;
  }
  if (t == 0) offs[N] = s_total;
}

// ---------------- scatter: packed int2{tgt, w_bits} ----------------
__global__ void scatter_kernel(const int* __restrict__ src, const int* __restrict__ tgt,
                               const float* __restrict__ ew, int* __restrict__ cursor,
                               int2* __restrict__ ews, int E) {
  int e = blockIdx.x * blockDim.x + threadIdx.x;
  if (e < E) {
    int pos = atomicAdd(&cursor[src[e]], 1);
    ews[pos] = make_int2(tgt[e], __float_as_int(ew[e]));
  }
}

// ---------------- per-node attention: one WAVE per node (round-4 structure) --
__global__ __launch_bounds__(256) void attn_kernel(
    const ushort* __restrict__ QKVb,
    const int* __restrict__ offs, const int2* __restrict__ ews,
    const float* __restrict__ We, ushort* __restrict__ AGGb, int N) {
  __shared__ float s_p[4][CH][8];
  __shared__ int s_tgt[4][CH];
  __shared__ float s_w[4][CH];
  int t = threadIdx.x;
  int w = t >> 6;
  int l = t & 63;
  int i = blockIdx.x * 4 + w;
  if (i >= N) return;
  int e8 = l >> 3;
  int h = l & 7;
  int hacc = l >> 3;
  const float scale = 0.17677669529663687f;
  float we = We[h];

  float qf[32];
  {
    const short8* qr = reinterpret_cast<const short8*>(QKVb + (size_t)i * 768 + h * 32);
#pragma unroll
    for (int d = 0; d < 4; ++d) {
      short8 qv = qr[d];
#pragma unroll
      for (int x = 0; x < 8; ++x) qf[d * 8 + x] = b2f((ushort)qv[x]);
    }
  }

  float m = -1e30f, lsum = 0.f;
  float acc0 = 0.f, acc1 = 0.f, acc2 = 0.f, acc3 = 0.f;
  int beg = offs[i], end = offs[i + 1];

  for (int base = beg; base < end; base += CH) {
    int cnt = min(CH, end - base);
    int cnt_pad = (cnt + 7) & ~7;  // >= 8 always
    {
      bool valid = l < cnt;
      int2 te = valid ? ews[base + l] : make_int2(i, 0);
      s_tgt[w][l] = te.x;
      s_w[w][l] = valid ? __int_as_float(te.y) : 0.f;
    }
    wave_lds_sync();

    // ---- score phase: depth-2 pipelined sections of 8 edges ----
    float s_local[8];
#pragma unroll
    for (int it = 0; it < 8; ++it) s_local[it] = -1e30f;

    short8 kc[4], kn[4];
    {
      const short8* p = reinterpret_cast<const short8*>(
          QKVb + (size_t)s_tgt[w][e8] * 768 + 256 + h * 32);
#pragma unroll
      for (int d = 0; d < 4; ++d) kc[d] = p[d];
    }
    if (8 < cnt_pad) {
      const short8* p = reinterpret_cast<const short8*>(
          QKVb + (size_t)s_tgt[w][8 + e8] * 768 + 256 + h * 32);
#pragma unroll
      for (int d = 0; d < 4; ++d) kn[d] = p[d];
    }
    float cmax = -1e30f;
#pragma unroll
    for (int it = 0; it < 8; ++it) {
      if (it * 8 >= cnt_pad) break;  // wave-uniform
      float dot = 0.f;
#pragma unroll
      for (int d = 0; d < 4; ++d)
#pragma unroll
        for (int x = 0; x < 8; ++x)
          dot += qf[d * 8 + x] * b2f((ushort)kc[d][x]);
      int j = it * 8 + e8;
      float s = (j < cnt) ? dot * scale + s_w[w][j] * we : -1e30f;
      s_local[it] = s;
      cmax = fmaxf(cmax, s);
#pragma unroll
      for (int d = 0; d < 4; ++d) kc[d] = kn[d];
      if ((it + 2) * 8 < cnt_pad) {
        const short8* p = reinterpret_cast<const short8*>(
            QKVb + (size_t)s_tgt[w][(it + 2) * 8 + e8] * 768 + 256 + h * 32);
#pragma unroll
        for (int d = 0; d < 4; ++d) kn[d] = p[d];
      }
    }
    cmax = fmaxf(cmax, __shfl_xor(cmax, 8));
    cmax = fmaxf(cmax, __shfl_xor(cmax, 16));
    cmax = fmaxf(cmax, __shfl_xor(cmax, 32));
    float newm = fmaxf(m, cmax);
    float f = __expf(m - newm);
    float psum = 0.f;
#pragma unroll
    for (int it = 0; it < 8; ++it) {
      if (it * 8 >= cnt_pad) break;
      int j = it * 8 + e8;
      float p = __expf(s_local[it] - newm);
      s_p[w][j][h] = p;
      psum += p;
    }
    psum += __shfl_xor(psum, 8);
    psum += __shfl_xor(psum, 16);
    psum += __shfl_xor(psum, 32);
    lsum = lsum * f + psum;
    m = newm;
    float f_acc = __shfl(f, hacc);
    acc0 *= f_acc; acc1 *= f_acc; acc2 *= f_acc; acc3 *= f_acc;
    wave_lds_sync();

    // ---- PV phase: 8-edge load batches ----
#pragma unroll
    for (int g = 0; g < 8; ++g) {
      if (g * 8 >= cnt_pad) break;
      float pv[8];
      short4_t vv[8];
#pragma unroll
      for (int k = 0; k < 8; ++k) {
        int j = g * 8 + k;
        pv[k] = s_p[w][j][hacc];
        vv[k] = *reinterpret_cast<const short4_t*>(
            QKVb + (size_t)s_tgt[w][j] * 768 + 512 + l * 4);
      }
#pragma unroll
      for (int k = 0; k < 8; ++k) {
        acc0 += pv[k] * b2f((ushort)vv[k][0]);
        acc1 += pv[k] * b2f((ushort)vv[k][1]);
        acc2 += pv[k] * b2f((ushort)vv[k][2]);
        acc3 += pv[k] * b2f((ushort)vv[k][3]);
      }
    }
    wave_lds_sync();
  }
  float lsum_acc = __shfl(lsum, hacc);
  float rinv = (lsum_acc > 0.f) ? 1.f / lsum_acc : 0.f;
  short4_t o;
  o[0] = (short)f2b(acc0 * rinv);
  o[1] = (short)f2b(acc1 * rinv);
  o[2] = (short)f2b(acc2 * rinv);
  o[3] = (short)f2b(acc3 * rinv);
  *reinterpret_cast<short4_t*>(AGGb + (size_t)i * 256 + l * 4) = o;
}

// ------- output GEMM (LDS-staged, BM=64 BN=256) + residual + LayerNorm ------
__global__ __launch_bounds__(256) void out_ln(
    const ushort* __restrict__ AGGb, const ushort* __restrict__ Wot,
    const float* __restrict__ X, const float* __restrict__ g, const float* __restrict__ bb,
    float* __restrict__ out, int N) {
  __shared__ ushort sA[64 * 64];
  __shared__ ushort sB[256 * 64];
  char* cA = (char*)sA;
  char* cB = (char*)sB;
  int t = threadIdx.x;
  int lane = t & 63, w = t >> 6;
  int row0 = blockIdx.x * 64;
  int lr = lane & 15, kg = lane >> 4;
  f32x4 acc[16] = {};
  for (int k0 = 0; k0 < 256; k0 += 64) {
#pragma unroll
    for (int it = 0; it < 2; ++it) {
      int slot = t + it * 256;
      int row = slot >> 3, kc = slot & 7;
      int grow = min(row0 + row, N - 1);
      short8 va = *reinterpret_cast<const short8*>(AGGb + (size_t)grow * 256 + k0 + kc * 8);
      *reinterpret_cast<short8*>(cA + ((row * 128 + kc * 16) ^ ((row & 7) << 4))) = va;
    }
#pragma unroll
    for (int it = 0; it < 8; ++it) {
      int slot = t + it * 256;
      int col = slot >> 3, kc = slot & 7;
      short8 vb = *reinterpret_cast<const short8*>(Wot + (size_t)col * 256 + k0 + kc * 8);
      *reinterpret_cast<short8*>(cB + ((col * 128 + kc * 16) ^ ((col & 7) << 4))) = vb;
    }
    __syncthreads();
#pragma unroll
    for (int ks = 0; ks < 2; ++ks) {
      int arow = w * 16 + lr;
      short8 a = *reinterpret_cast<const short8*>(
          cA + ((arow * 128 + ks * 64 + kg * 16) ^ ((arow & 7) << 4)));
#pragma unroll
      for (int fc = 0; fc < 16; ++fc) {
        int col = fc * 16 + lr;
        short8 b = *reinterpret_cast<const short8*>(
            cB + ((col * 128 + ks * 64 + kg * 16) ^ ((col & 7) << 4)));
        acc[fc] = __builtin_amdgcn_mfma_f32_16x16x32_bf16(a, b, acc[fc], 0, 0, 0);
      }
    }
    __syncthreads();
  }
  float g16[16], b16[16];
#pragma unroll
  for (int fc = 0; fc < 16; ++fc) {
    g16[fc] = g[fc * 16 + lr];
    b16[fc] = bb[fc * 16 + lr];
  }
#pragma unroll
  for (int r = 0; r < 4; ++r) {
    int rowl = kg * 4 + r;
    int grow = row0 + w * 16 + rowl;
    int growc = min(grow, N - 1);
    float xv[16];
    float s = 0.f, ss = 0.f;
#pragma unroll
    for (int fc = 0; fc < 16; ++fc) {
      float v = acc[fc][r] + X[(size_t)growc * 256 + fc * 16 + lr];
      xv[fc] = v;
      s += v;
      ss += v * v;
    }
    s += __shfl_xor(s, 1);  ss += __shfl_xor(ss, 1);
    s += __shfl_xor(s, 2);  ss += __shfl_xor(ss, 2);
    s += __shfl_xor(s, 4);  ss += __shfl_xor(ss, 4);
    s += __shfl_xor(s, 8);  ss += __shfl_xor(ss, 8);
    float mu = s * (1.f / 256.f);
    float var = ss * (1.f / 256.f) - mu * mu;
    float rs = rsqrtf(var + 1e-5f);
    if (grow < N) {
#pragma unroll
      for (int fc = 0; fc < 16; ++fc)
        out[(size_t)grow * 256 + fc * 16 + lr] = (xv[fc] - mu) * rs * g16[fc] + b16[fc];
    }
  }
}

extern "C" void kernel_launch(void* const* d_in, const int* in_sizes, int n_in,
                              void* d_out, int out_size, void* d_ws, size_t ws_size,
                              hipStream_t stream) {
  const float* X  = (const float*)d_in[0];
  const int* eidx = (const int*)d_in[1];
  const float* ew = (const float*)d_in[2];
  const float* Wq = (const float*)d_in[3];
  const float* Wk = (const float*)d_in[4];
  const float* Wv = (const float*)d_in[5];
  const float* We = (const float*)d_in[6];
  const float* Wo = (const float*)d_in[7];
  const float* g  = (const float*)d_in[8];
  const float* b  = (const float*)d_in[9];
  int N = in_sizes[0] / 256;
  int E = in_sizes[1] / 2;
  const int* src = eidx;
  const int* tgt = eidx + E;
  float* out = (float*)d_out;

  char* w = (char*)d_ws;
  ushort* Wt   = (ushort*)w;  w += (size_t)1024 * 256 * 2;
  ushort* QKVb = (ushort*)w;  w += (size_t)N * 768 * 2;
  ushort* AGGb = (ushort*)w;  w += (size_t)N * 256 * 2;
  int* counts  = (int*)w;     w += (size_t)N * 4;
  int* offs    = (int*)w;     w += (size_t)(N + 1) * 4;
  int* cursor  = (int*)w;     w += (size_t)N * 4;
  int2* ews    = (int2*)w;    w += (size_t)E * 8;
  const ushort* Wot = Wt + (size_t)768 * 256;

  hipMemsetAsync(counts, 0, (size_t)N * 4, stream);

  int nhist = (E + 255) / 256;
  pre_kernel<<<256 + nhist, 256, 0, stream>>>(Wq, Wk, Wv, Wo, Wt, src, counts, E);

  int ngemm = ((N + 127) / 128) * 6;
  qkv_gemm<<<ngemm, 256, 0, stream>>>(X, Wt, QKVb, N);

  scan_kernel<<<1, 1024, 0, stream>>>(counts, offs, cursor, N);
  scatter_kernel<<<(E + 255) / 256, 256, 0, stream>>>(src, tgt, ew, cursor, ews, E);
  attn_kernel<<<(N + 3) / 4, 256, 0, stream>>>(QKVb, offs, ews, We, AGGb, N);
  out_ln<<<(N + 63) / 64, 256, 0, stream>>>(AGGb, Wot, X, g, b, out, N);
}

// Round 10
// 154.489 us; speedup vs baseline: 1.1181x; 1.0364x over previous
//
#include <hip/hip_runtime.h>
#include <hip/hip_bf16.h>
#include <hip/hip_fp8.h>

typedef __attribute__((ext_vector_type(8))) short short8;
typedef __attribute__((ext_vector_type(16))) unsigned char uchar16;
typedef __attribute__((ext_vector_type(4))) float f32x4;

#define CH 64

__device__ __forceinline__ ushort f2b(float f) {
  __hip_bfloat16 h = __float2bfloat16(f);
  return *reinterpret_cast<ushort*>(&h);
}
__device__ __forceinline__ float b2f(ushort u) {
  return __uint_as_float(((unsigned)u) << 16);
}
__device__ __forceinline__ unsigned char f2e4(float f) {
  __hip_fp8_e4m3 h(f);
  return *reinterpret_cast<unsigned char*>(&h);
}
__device__ __forceinline__ float e42f(unsigned char u) {
  __hip_fp8_e4m3 h;
  *reinterpret_cast<unsigned char*>(&h) = u;
  return (float)h;
}
__device__ __forceinline__ void wave_lds_sync() {
  asm volatile("s_waitcnt lgkmcnt(0)" ::: "memory");
  __builtin_amdgcn_wave_barrier();
}

// ------ pre: convert X->bf16, convert+transpose W, zero counts --------------
__global__ __launch_bounds__(256) void pre_kernel(
    const float* __restrict__ X, ushort* __restrict__ Xb, int nX,
    const float* __restrict__ Wq, const float* __restrict__ Wk,
    const float* __restrict__ Wv, const float* __restrict__ Wo,
    ushort* __restrict__ Wt, int* __restrict__ counts, int N, int nxb) {
  __shared__ float L[32][33];
  int b = blockIdx.x;
  int t = threadIdx.x;
  if (b < nxb) {
    int i = (b * 256 + t) * 8;
    if (i >= nX) return;
    float4 x0 = *reinterpret_cast<const float4*>(X + i);
    float4 x1 = *reinterpret_cast<const float4*>(X + i + 4);
    short8 o;
    o[0] = (short)f2b(x0.x); o[1] = (short)f2b(x0.y);
    o[2] = (short)f2b(x0.z); o[3] = (short)f2b(x0.w);
    o[4] = (short)f2b(x1.x); o[5] = (short)f2b(x1.y);
    o[6] = (short)f2b(x1.z); o[7] = (short)f2b(x1.w);
    *reinterpret_cast<short8*>(Xb + i) = o;
  } else if (b < nxb + 256) {
    int bx = b - nxb;
    int mat = bx >> 6;
    int tile = bx & 63;
    int tr = (tile >> 3) * 32;
    int tc = (tile & 7) * 32;
    const float* W = (mat == 0) ? Wq : (mat == 1) ? Wk : (mat == 2) ? Wv : Wo;
    int c = t & 31, r8 = t >> 5;
#pragma unroll
    for (int rr = 0; rr < 4; ++rr) {
      int r = r8 + rr * 8;
      L[r][c] = W[(size_t)(tr + r) * 256 + tc + c];
    }
    __syncthreads();
#pragma unroll
    for (int rr = 0; rr < 4; ++rr) {
      int cc = r8 + rr * 8;
      Wt[(size_t)(mat * 256 + tc + cc) * 256 + tr + c] = f2b(L[c][cc]);
    }
  } else {
    int i = (b - nxb - 256) * 256 + t;
    if (i < N) counts[i] = 0;
  }
}

// ------ fused: QKV MFMA GEMM (LDS-staged, swizzled, XCD-chunked) + hist -----
// Q cols (by 0,1) -> bf16 Qb; K cols (by 2,3) -> fp8 Kb8; V cols (by 4,5) -> fp8 Vb8.
__global__ __launch_bounds__(256) void gemm_hist(
    const ushort* __restrict__ Xb, const ushort* __restrict__ Wt,
    ushort* __restrict__ Qb, unsigned char* __restrict__ Kb8,
    unsigned char* __restrict__ Vb8, const int* __restrict__ src,
    int* __restrict__ counts, int N, int E, int ngemm) {
  __shared__ ushort sA[128 * 64];
  __shared__ ushort sB[128 * 64];
  int bid = blockIdx.x;
  int t = threadIdx.x;
  if (bid >= ngemm) {
    int e = (bid - ngemm) * 256 + t;
    if (e < E) atomicAdd(&counts[src[e]], 1);
    return;
  }
  // XCD-bijective swizzle (m204) over gemm blocks: panel-sharing blocks -> one XCD
  int q = ngemm >> 3, r = ngemm & 7;
  int xcd = bid & 7;
  int wgid = (xcd < r ? xcd * (q + 1) : r * (q + 1) + (xcd - r) * q) + (bid >> 3);
  int bx = wgid / 6, by = wgid % 6;
  char* cA = (char*)sA;
  char* cB = (char*)sB;
  int lane = t & 63, w = t >> 6;
  int wr = w >> 1, wc = w & 1;
  int row0 = bx * 128;
  int lr = lane & 15, kg = lane >> 4;
  f32x4 acc[4][4] = {};
  for (int k0 = 0; k0 < 256; k0 += 64) {
#pragma unroll
    for (int it = 0; it < 4; ++it) {
      int slot = t + it * 256;
      int row = slot >> 3, kc = slot & 7;
      int grow = min(row0 + row, N - 1);
      short8 va = *reinterpret_cast<const short8*>(Xb + (size_t)grow * 256 + k0 + kc * 8);
      *reinterpret_cast<short8*>(cA + ((row * 128 + kc * 16) ^ ((row & 7) << 4))) = va;
      short8 vb = *reinterpret_cast<const short8*>(Wt + (size_t)(by * 128 + row) * 256 + k0 + kc * 8);
      *reinterpret_cast<short8*>(cB + ((row * 128 + kc * 16) ^ ((row & 7) << 4))) = vb;
    }
    __syncthreads();
#pragma unroll
    for (int ks = 0; ks < 2; ++ks) {
      short8 af[4], bf[4];
#pragma unroll
      for (int fr = 0; fr < 4; ++fr) {
        int row = wr * 64 + fr * 16 + lr;
        af[fr] = *reinterpret_cast<const short8*>(
            cA + ((row * 128 + ks * 64 + kg * 16) ^ ((row & 7) << 4)));
      }
#pragma unroll
      for (int fc = 0; fc < 4; ++fc) {
        int col = wc * 64 + fc * 16 + lr;
        bf[fc] = *reinterpret_cast<const short8*>(
            cB + ((col * 128 + ks * 64 + kg * 16) ^ ((col & 7) << 4)));
      }
#pragma unroll
      for (int fr = 0; fr < 4; ++fr)
#pragma unroll
        for (int fc = 0; fc < 4; ++fc)
          acc[fr][fc] = __builtin_amdgcn_mfma_f32_16x16x32_bf16(af[fr], bf[fc], acc[fr][fc], 0, 0, 0);
    }
    __syncthreads();
  }
  int orow = kg * 4;
  int mat = by >> 1;  // 0=Q, 1=K, 2=V
#pragma unroll
  for (int fr = 0; fr < 4; ++fr)
#pragma unroll
    for (int fc = 0; fc < 4; ++fc)
#pragma unroll
      for (int r2 = 0; r2 < 4; ++r2) {
        int row = row0 + wr * 64 + fr * 16 + orow + r2;
        int col = (by & 1) * 128 + wc * 64 + fc * 16 + lr;  // 0..255 within matrix
        if (row < N) {
          float v = acc[fr][fc][r2];
          if (mat == 0)      Qb[(size_t)row * 256 + col]  = f2b(v);
          else if (mat == 1) Kb8[(size_t)row * 256 + col] = f2e4(v);
          else               Vb8[(size_t)row * 256 + col] = f2e4(v);
        }
      }
}

// ---------------- scan: single block, 1024 threads ----------------
__global__ __launch_bounds__(1024) void scan_kernel(
    const int* __restrict__ counts, int* __restrict__ offs, int* __restrict__ cursor, int N) {
  __shared__ int wsum[16];
  __shared__ int wexc[16];
  __shared__ int s_total;
  int t = threadIdx.x;
  int lane = t & 63, wv = t >> 6;
  int per = (N + 1023) >> 10;
  int b0 = t * per;
  int e0 = min(b0 + per, N);
  int sum = 0;
  for (int i = b0; i < e0; ++i) sum += counts[i];
  int x = sum;
#pragma unroll
  for (int off = 1; off < 64; off <<= 1) {
    int y = __shfl_up(x, off);
    if (lane >= off) x += y;
  }
  if (lane == 63) wsum[wv] = x;
  __syncthreads();
  if (t < 64) {
    int s = (lane < 16) ? wsum[lane] : 0;
    int xs = s;
#pragma unroll
    for (int off = 1; off < 16; off <<= 1) {
      int y = __shfl_up(xs, off);
      if (lane >= off) xs += y;
    }
    if (lane < 16) wexc[lane] = xs - s;
    if (lane == 15) s_total = xs;
  }
  __syncthreads();
  int running = wexc[wv] + (x - sum);
  for (int i = b0; i < e0; ++i) {
    int c = counts[i];
    offs[i] = running;
    cursor[i] = running;
    running += c;
  }
  if (t == 0) offs[N] = s_total;
}

// ---------------- scatter: packed int2{tgt, w_bits} ----------------
__global__ void scatter_kernel(const int* __restrict__ src, const int* __restrict__ tgt,
                               const float* __restrict__ ew, int* __restrict__ cursor,
                               int2* __restrict__ ews, int E) {
  int e = blockIdx.x * blockDim.x + threadIdx.x;
  if (e < E) {
    int pos = atomicAdd(&cursor[src[e]], 1);
    ews[pos] = make_int2(tgt[e], __float_as_int(ew[e]));
  }
}

// -------- per-node attention: one WAVE per node; fp8 K/V gathers ------------
__global__ __launch_bounds__(256) void attn_kernel(
    const ushort* __restrict__ Qb, const unsigned char* __restrict__ Kb8,
    const unsigned char* __restrict__ Vb8,
    const int* __restrict__ offs, const int2* __restrict__ ews,
    const float* __restrict__ We, ushort* __restrict__ AGGb, int N) {
  __shared__ float s_p[4][CH][8];
  __shared__ int s_tgt[4][CH];
  __shared__ float s_w[4][CH];
  int t = threadIdx.x;
  int w = t >> 6;
  int l = t & 63;
  int i = blockIdx.x * 4 + w;
  if (i >= N) return;
  int e8 = l >> 3;
  int h = l & 7;
  int hacc = l >> 3;
  const float scale = 0.17677669529663687f;
  float we = We[h];

  float qf[32];
  {
    const short8* qr = reinterpret_cast<const short8*>(Qb + (size_t)i * 256 + h * 32);
#pragma unroll
    for (int d = 0; d < 4; ++d) {
      short8 qv = qr[d];
#pragma unroll
      for (int x = 0; x < 8; ++x) qf[d * 8 + x] = b2f((ushort)qv[x]);
    }
  }

  float m = -1e30f, lsum = 0.f;
  float acc0 = 0.f, acc1 = 0.f, acc2 = 0.f, acc3 = 0.f;
  int beg = offs[i], end = offs[i + 1];

  for (int base = beg; base < end; base += CH) {
    int cnt = min(CH, end - base);
    int cnt_pad = (cnt + 7) & ~7;  // >= 8 always
    {
      bool valid = l < cnt;
      int2 te = valid ? ews[base + l] : make_int2(i, 0);
      s_tgt[w][l] = te.x;
      s_w[w][l] = valid ? __int_as_float(te.y) : 0.f;
    }
    wave_lds_sync();

    // ---- score phase: depth-2 pipelined sections of 8 edges, fp8 K ----
    float s_local[8];
#pragma unroll
    for (int it = 0; it < 8; ++it) s_local[it] = -1e30f;

    uchar16 kc[2], kn[2];
    {
      const uchar16* p = reinterpret_cast<const uchar16*>(
          Kb8 + (size_t)s_tgt[w][e8] * 256 + h * 32);
      kc[0] = p[0]; kc[1] = p[1];
    }
    if (8 < cnt_pad) {
      const uchar16* p = reinterpret_cast<const uchar16*>(
          Kb8 + (size_t)s_tgt[w][8 + e8] * 256 + h * 32);
      kn[0] = p[0]; kn[1] = p[1];
    }
    float cmax = -1e30f;
#pragma unroll
    for (int it = 0; it < 8; ++it) {
      if (it * 8 >= cnt_pad) break;  // wave-uniform
      float dot = 0.f;
#pragma unroll
      for (int c = 0; c < 2; ++c)
#pragma unroll
        for (int x = 0; x < 16; ++x)
          dot += qf[c * 16 + x] * e42f(kc[c][x]);
      int j = it * 8 + e8;
      float s = (j < cnt) ? dot * scale + s_w[w][j] * we : -1e30f;
      s_local[it] = s;
      cmax = fmaxf(cmax, s);
      kc[0] = kn[0]; kc[1] = kn[1];
      if ((it + 2) * 8 < cnt_pad) {
        const uchar16* p = reinterpret_cast<const uchar16*>(
            Kb8 + (size_t)s_tgt[w][(it + 2) * 8 + e8] * 256 + h * 32);
        kn[0] = p[0]; kn[1] = p[1];
      }
    }
    cmax = fmaxf(cmax, __shfl_xor(cmax, 8));
    cmax = fmaxf(cmax, __shfl_xor(cmax, 16));
    cmax = fmaxf(cmax, __shfl_xor(cmax, 32));
    float newm = fmaxf(m, cmax);
    float f = __expf(m - newm);
    float psum = 0.f;
#pragma unroll
    for (int it = 0; it < 8; ++it) {
      if (it * 8 >= cnt_pad) break;
      int j = it * 8 + e8;
      float p = __expf(s_local[it] - newm);
      s_p[w][j][h] = p;
      psum += p;
    }
    psum += __shfl_xor(psum, 8);
    psum += __shfl_xor(psum, 16);
    psum += __shfl_xor(psum, 32);
    lsum = lsum * f + psum;
    m = newm;
    float f_acc = __shfl(f, hacc);
    acc0 *= f_acc; acc1 *= f_acc; acc2 *= f_acc; acc3 *= f_acc;
    wave_lds_sync();

    // ---- PV phase: 8-edge load batches, fp8 V (4B/lane) ----
#pragma unroll
    for (int g = 0; g < 8; ++g) {
      if (g * 8 >= cnt_pad) break;
      float pv[8];
      unsigned vv[8];
#pragma unroll
      for (int k = 0; k < 8; ++k) {
        int j = g * 8 + k;
        pv[k] = s_p[w][j][hacc];
        vv[k] = *reinterpret_cast<const unsigned*>(
            Vb8 + (size_t)s_tgt[w][j] * 256 + l * 4);
      }
#pragma unroll
      for (int k = 0; k < 8; ++k) {
        acc0 += pv[k] * e42f((unsigned char)(vv[k] & 0xff));
        acc1 += pv[k] * e42f((unsigned char)((vv[k] >> 8) & 0xff));
        acc2 += pv[k] * e42f((unsigned char)((vv[k] >> 16) & 0xff));
        acc3 += pv[k] * e42f((unsigned char)(vv[k] >> 24));
      }
    }
    wave_lds_sync();
  }
  float lsum_acc = __shfl(lsum, hacc);
  float rinv = (lsum_acc > 0.f) ? 1.f / lsum_acc : 0.f;
  ushort o0 = f2b(acc0 * rinv), o1 = f2b(acc1 * rinv);
  ushort o2 = f2b(acc2 * rinv), o3 = f2b(acc3 * rinv);
  short8 dummy;
  ushort4 o = make_ushort4(o0, o1, o2, o3);
  *reinterpret_cast<ushort4*>(AGGb + (size_t)i * 256 + l * 4) = o;
  (void)dummy;
}

// ------- output GEMM (LDS-staged, BM=64 BN=256) + residual + LayerNorm ------
__global__ __launch_bounds__(256) void out_ln(
    const ushort* __restrict__ AGGb, const ushort* __restrict__ Wot,
    const float* __restrict__ X, const float* __restrict__ g, const float* __restrict__ bb,
    float* __restrict__ out, int N) {
  __shared__ ushort sA[64 * 64];
  __shared__ ushort sB[256 * 64];
  char* cA = (char*)sA;
  char* cB = (char*)sB;
  int t = threadIdx.x;
  int lane = t & 63, w = t >> 6;
  int row0 = blockIdx.x * 64;
  int lr = lane & 15, kg = lane >> 4;
  f32x4 acc[16] = {};
  for (int k0 = 0; k0 < 256; k0 += 64) {
#pragma unroll
    for (int it = 0; it < 2; ++it) {
      int slot = t + it * 256;
      int row = slot >> 3, kc = slot & 7;
      int grow = min(row0 + row, N - 1);
      short8 va = *reinterpret_cast<const short8*>(AGGb + (size_t)grow * 256 + k0 + kc * 8);
      *reinterpret_cast<short8*>(cA + ((row * 128 + kc * 16) ^ ((row & 7) << 4))) = va;
    }
#pragma unroll
    for (int it = 0; it < 8; ++it) {
      int slot = t + it * 256;
      int col = slot >> 3, kc = slot & 7;
      short8 vb = *reinterpret_cast<const short8*>(Wot + (size_t)col * 256 + k0 + kc * 8);
      *reinterpret_cast<short8*>(cB + ((col * 128 + kc * 16) ^ ((col & 7) << 4))) = vb;
    }
    __syncthreads();
#pragma unroll
    for (int ks = 0; ks < 2; ++ks) {
      int arow = w * 16 + lr;
      short8 a = *reinterpret_cast<const short8*>(
          cA + ((arow * 128 + ks * 64 + kg * 16) ^ ((arow & 7) << 4)));
#pragma unroll
      for (int fc = 0; fc < 16; ++fc) {
        int col = fc * 16 + lr;
        short8 b = *reinterpret_cast<const short8*>(
            cB + ((col * 128 + ks * 64 + kg * 16) ^ ((col & 7) << 4)));
        acc[fc] = __builtin_amdgcn_mfma_f32_16x16x32_bf16(a, b, acc[fc], 0, 0, 0);
      }
    }
    __syncthreads();
  }
  float g16[16], b16[16];
#pragma unroll
  for (int fc = 0; fc < 16; ++fc) {
    g16[fc] = g[fc * 16 + lr];
    b16[fc] = bb[fc * 16 + lr];
  }
#pragma unroll
  for (int r = 0; r < 4; ++r) {
    int rowl = kg * 4 + r;
    int grow = row0 + w * 16 + rowl;
    int growc = min(grow, N - 1);
    float xv[16];
    float s = 0.f, ss = 0.f;
#pragma unroll
    for (int fc = 0; fc < 16; ++fc) {
      float v = acc[fc][r] + X[(size_t)growc * 256 + fc * 16 + lr];
      xv[fc] = v;
      s += v;
      ss += v * v;
    }
    s += __shfl_xor(s, 1);  ss += __shfl_xor(ss, 1);
    s += __shfl_xor(s, 2);  ss += __shfl_xor(ss, 2);
    s += __shfl_xor(s, 4);  ss += __shfl_xor(ss, 4);
    s += __shfl_xor(s, 8);  ss += __shfl_xor(ss, 8);
    float mu = s * (1.f / 256.f);
    float var = ss * (1.f / 256.f) - mu * mu;
    float rs = rsqrtf(var + 1e-5f);
    if (grow < N) {
#pragma unroll
      for (int fc = 0; fc < 16; ++fc)
        out[(size_t)grow * 256 + fc * 16 + lr] = (xv[fc] - mu) * rs * g16[fc] + b16[fc];
    }
  }
}

extern "C" void kernel_launch(void* const* d_in, const int* in_sizes, int n_in,
                              void* d_out, int out_size, void* d_ws, size_t ws_size,
                              hipStream_t stream) {
  const float* X  = (const float*)d_in[0];
  const int* eidx = (const int*)d_in[1];
  const float* ew = (const float*)d_in[2];
  const float* Wq = (const float*)d_in[3];
  const float* Wk = (const float*)d_in[4];
  const float* Wv = (const float*)d_in[5];
  const float* We = (const float*)d_in[6];
  const float* Wo = (const float*)d_in[7];
  const float* g  = (const float*)d_in[8];
  const float* b  = (const float*)d_in[9];
  int N = in_sizes[0] / 256;
  int E = in_sizes[1] / 2;
  const int* src = eidx;
  const int* tgt = eidx + E;
  float* out = (float*)d_out;

  char* w = (char*)d_ws;
  ushort* Xb   = (ushort*)w;        w += (size_t)N * 256 * 2;
  ushort* Wt   = (ushort*)w;        w += (size_t)1024 * 256 * 2;
  ushort* Qb   = (ushort*)w;        w += (size_t)N * 256 * 2;
  unsigned char* Kb8 = (unsigned char*)w;  w += (size_t)N * 256;
  unsigned char* Vb8 = (unsigned char*)w;  w += (size_t)N * 256;
  ushort* AGGb = (ushort*)w;        w += (size_t)N * 256 * 2;
  int* counts  = (int*)w;           w += (size_t)N * 4;
  int* offs    = (int*)w;           w += (size_t)(N + 1) * 4;
  int* cursor  = (int*)w;           w += (size_t)N * 4;
  int2* ews    = (int2*)w;          w += (size_t)E * 8;
  const ushort* Wot = Wt + (size_t)768 * 256;

  int nX = N * 256;
  int nxb = (nX / 8 + 255) / 256;
  int nzero = (N + 255) / 256;
  pre_kernel<<<nxb + 256 + nzero, 256, 0, stream>>>(X, Xb, nX, Wq, Wk, Wv, Wo, Wt, counts, N, nxb);

  int ngemm = ((N + 127) / 128) * 6;
  int nhist = (E + 255) / 256;
  gemm_hist<<<ngemm + nhist, 256, 0, stream>>>(Xb, Wt, Qb, Kb8, Vb8, src, counts, N, E, ngemm);

  scan_kernel<<<1, 1024, 0, stream>>>(counts, offs, cursor, N);
  scatter_kernel<<<(E + 255) / 256, 256, 0, stream>>>(src, tgt, ew, cursor, ews, E);
  attn_kernel<<<(N + 3) / 4, 256, 0, stream>>>(Qb, Kb8, Vb8, offs, ews, We, AGGb, N);
  out_ln<<<(N + 63) / 64, 256, 0, stream>>>(AGGb, Wot, X, g, b, out, N);
}

// Round 11
// 147.237 us; speedup vs baseline: 1.1731x; 1.0493x over previous
//
#include <hip/hip_runtime.h>
#include <hip/hip_bf16.h>

typedef __attribute__((ext_vector_type(8))) short short8;
typedef __attribute__((ext_vector_type(4))) int intx4;
typedef __attribute__((ext_vector_type(2))) float floatx2;
typedef __attribute__((ext_vector_type(4))) float f32x4;

#define CH 64

__device__ __forceinline__ ushort f2b(float f) {
  __hip_bfloat16 h = __float2bfloat16(f);
  return *reinterpret_cast<ushort*>(&h);
}
__device__ __forceinline__ float b2f(ushort u) {
  return __uint_as_float(((unsigned)u) << 16);
}
// HW fp8 e4m3 (OCP on gfx950) encode: 1 inst/value
__device__ __forceinline__ unsigned char f2e4(float f) {
  int p = __builtin_amdgcn_cvt_pk_fp8_f32(f, f, 0, false);
  return (unsigned char)(p & 0xff);
}
__device__ __forceinline__ void wave_lds_sync() {
  asm volatile("s_waitcnt lgkmcnt(0)" ::: "memory");
  __builtin_amdgcn_wave_barrier();
}

// ------ pre: convert X->bf16, convert+transpose W, zero counts --------------
__global__ __launch_bounds__(256) void pre_kernel(
    const float* __restrict__ X, ushort* __restrict__ Xb, int nX,
    const float* __restrict__ Wq, const float* __restrict__ Wk,
    const float* __restrict__ Wv, const float* __restrict__ Wo,
    ushort* __restrict__ Wt, int* __restrict__ counts, int N, int nxb) {
  __shared__ float L[32][33];
  int b = blockIdx.x;
  int t = threadIdx.x;
  if (b < nxb) {
    int i = (b * 256 + t) * 8;
    if (i >= nX) return;
    float4 x0 = *reinterpret_cast<const float4*>(X + i);
    float4 x1 = *reinterpret_cast<const float4*>(X + i + 4);
    short8 o;
    o[0] = (short)f2b(x0.x); o[1] = (short)f2b(x0.y);
    o[2] = (short)f2b(x0.z); o[3] = (short)f2b(x0.w);
    o[4] = (short)f2b(x1.x); o[5] = (short)f2b(x1.y);
    o[6] = (short)f2b(x1.z); o[7] = (short)f2b(x1.w);
    *reinterpret_cast<short8*>(Xb + i) = o;
  } else if (b < nxb + 256) {
    int bx = b - nxb;
    int mat = bx >> 6;
    int tile = bx & 63;
    int tr = (tile >> 3) * 32;
    int tc = (tile & 7) * 32;
    const float* W = (mat == 0) ? Wq : (mat == 1) ? Wk : (mat == 2) ? Wv : Wo;
    int c = t & 31, r8 = t >> 5;
#pragma unroll
    for (int rr = 0; rr < 4; ++rr) {
      int r = r8 + rr * 8;
      L[r][c] = W[(size_t)(tr + r) * 256 + tc + c];
    }
    __syncthreads();
#pragma unroll
    for (int rr = 0; rr < 4; ++rr) {
      int cc = r8 + rr * 8;
      Wt[(size_t)(mat * 256 + tc + cc) * 256 + tr + c] = f2b(L[c][cc]);
    }
  } else {
    int i = (b - nxb - 256) * 256 + t;
    if (i < N) counts[i] = 0;
  }
}

// ------ fused: QKV MFMA GEMM (LDS-staged, swizzled, XCD-chunked) + hist -----
// Q cols (by 0,1) -> bf16 Qb; K cols (by 2,3) -> fp8 Kb8; V cols (by 4,5) -> fp8 Vb8.
__global__ __launch_bounds__(256) void gemm_hist(
    const ushort* __restrict__ Xb, const ushort* __restrict__ Wt,
    ushort* __restrict__ Qb, unsigned char* __restrict__ Kb8,
    unsigned char* __restrict__ Vb8, const int* __restrict__ src,
    int* __restrict__ counts, int N, int E, int ngemm) {
  __shared__ ushort sA[128 * 64];
  __shared__ ushort sB[128 * 64];
  int bid = blockIdx.x;
  int t = threadIdx.x;
  if (bid >= ngemm) {
    int e = (bid - ngemm) * 256 + t;
    if (e < E) atomicAdd(&counts[src[e]], 1);
    return;
  }
  // XCD-bijective swizzle (m204): panel-sharing blocks -> one XCD
  int q = ngemm >> 3, r = ngemm & 7;
  int xcd = bid & 7;
  int wgid = (xcd < r ? xcd * (q + 1) : r * (q + 1) + (xcd - r) * q) + (bid >> 3);
  int bx = wgid / 6, by = wgid % 6;
  char* cA = (char*)sA;
  char* cB = (char*)sB;
  int lane = t & 63, w = t >> 6;
  int wr = w >> 1, wc = w & 1;
  int row0 = bx * 128;
  int lr = lane & 15, kg = lane >> 4;
  f32x4 acc[4][4] = {};
  for (int k0 = 0; k0 < 256; k0 += 64) {
#pragma unroll
    for (int it = 0; it < 4; ++it) {
      int slot = t + it * 256;
      int row = slot >> 3, kc = slot & 7;
      int grow = min(row0 + row, N - 1);
      short8 va = *reinterpret_cast<const short8*>(Xb + (size_t)grow * 256 + k0 + kc * 8);
      *reinterpret_cast<short8*>(cA + ((row * 128 + kc * 16) ^ ((row & 7) << 4))) = va;
      short8 vb = *reinterpret_cast<const short8*>(Wt + (size_t)(by * 128 + row) * 256 + k0 + kc * 8);
      *reinterpret_cast<short8*>(cB + ((row * 128 + kc * 16) ^ ((row & 7) << 4))) = vb;
    }
    __syncthreads();
#pragma unroll
    for (int ks = 0; ks < 2; ++ks) {
      short8 af[4], bf[4];
#pragma unroll
      for (int fr = 0; fr < 4; ++fr) {
        int row = wr * 64 + fr * 16 + lr;
        af[fr] = *reinterpret_cast<const short8*>(
            cA + ((row * 128 + ks * 64 + kg * 16) ^ ((row & 7) << 4)));
      }
#pragma unroll
      for (int fc = 0; fc < 4; ++fc) {
        int col = wc * 64 + fc * 16 + lr;
        bf[fc] = *reinterpret_cast<const short8*>(
            cB + ((col * 128 + ks * 64 + kg * 16) ^ ((col & 7) << 4)));
      }
#pragma unroll
      for (int fr = 0; fr < 4; ++fr)
#pragma unroll
        for (int fc = 0; fc < 4; ++fc)
          acc[fr][fc] = __builtin_amdgcn_mfma_f32_16x16x32_bf16(af[fr], bf[fc], acc[fr][fc], 0, 0, 0);
    }
    __syncthreads();
  }
  int orow = kg * 4;
  int mat = by >> 1;  // 0=Q, 1=K, 2=V
#pragma unroll
  for (int fr = 0; fr < 4; ++fr)
#pragma unroll
    for (int fc = 0; fc < 4; ++fc)
#pragma unroll
      for (int r2 = 0; r2 < 4; ++r2) {
        int row = row0 + wr * 64 + fr * 16 + orow + r2;
        int col = (by & 1) * 128 + wc * 64 + fc * 16 + lr;  // 0..255 within matrix
        if (row < N) {
          float v = acc[fr][fc][r2];
          if (mat == 0)      Qb[(size_t)row * 256 + col]  = f2b(v);
          else if (mat == 1) Kb8[(size_t)row * 256 + col] = f2e4(v);
          else               Vb8[(size_t)row * 256 + col] = f2e4(v);
        }
      }
}

// ---------------- scan: single block, 1024 threads ----------------
__global__ __launch_bounds__(1024) void scan_kernel(
    const int* __restrict__ counts, int* __restrict__ offs, int* __restrict__ cursor, int N) {
  __shared__ int wsum[16];
  __shared__ int wexc[16];
  __shared__ int s_total;
  int t = threadIdx.x;
  int lane = t & 63, wv = t >> 6;
  int per = (N + 1023) >> 10;
  int b0 = t * per;
  int e0 = min(b0 + per, N);
  int sum = 0;
  for (int i = b0; i < e0; ++i) sum += counts[i];
  int x = sum;
#pragma unroll
  for (int off = 1; off < 64; off <<= 1) {
    int y = __shfl_up(x, off);
    if (lane >= off) x += y;
  }
  if (lane == 63) wsum[wv] = x;
  __syncthreads();
  if (t < 64) {
    int s = (lane < 16) ? wsum[lane] : 0;
    int xs = s;
#pragma unroll
    for (int off = 1; off < 16; off <<= 1) {
      int y = __shfl_up(xs, off);
      if (lane >= off) xs += y;
    }
    if (lane < 16) wexc[lane] = xs - s;
    if (lane == 15) s_total = xs;
  }
  __syncthreads();
  int running = wexc[wv] + (x - sum);
  for (int i = b0; i < e0; ++i) {
    int c = counts[i];
    offs[i] = running;
    cursor[i] = running;
    running += c;
  }
  if (t == 0) offs[N] = s_total;
}

// ---------------- scatter: packed int2{tgt, w_bits} ----------------
__global__ void scatter_kernel(const int* __restrict__ src, const int* __restrict__ tgt,
                               const float* __restrict__ ew, int* __restrict__ cursor,
                               int2* __restrict__ ews, int E) {
  int e = blockIdx.x * blockDim.x + threadIdx.x;
  if (e < E) {
    int pos = atomicAdd(&cursor[src[e]], 1);
    ews[pos] = make_int2(tgt[e], __float_as_int(ew[e]));
  }
}

// -------- per-node attention: one WAVE per node; fp8 K/V + HW cvt -----------
__global__ __launch_bounds__(256) void attn_kernel(
    const ushort* __restrict__ Qb, const unsigned char* __restrict__ Kb8,
    const unsigned char* __restrict__ Vb8,
    const int* __restrict__ offs, const int2* __restrict__ ews,
    const float* __restrict__ We, ushort* __restrict__ AGGb, int N) {
  __shared__ float s_p[4][CH][8];
  __shared__ int s_tgt[4][CH];
  __shared__ float s_w[4][CH];
  int t = threadIdx.x;
  int w = t >> 6;
  int l = t & 63;
  int i = blockIdx.x * 4 + w;
  if (i >= N) return;
  int e8 = l >> 3;
  int h = l & 7;
  int hacc = l >> 3;
  const float scale = 0.17677669529663687f;
  float we = We[h];

  float qf[32];
  {
    const short8* qr = reinterpret_cast<const short8*>(Qb + (size_t)i * 256 + h * 32);
#pragma unroll
    for (int d = 0; d < 4; ++d) {
      short8 qv = qr[d];
#pragma unroll
      for (int x = 0; x < 8; ++x) qf[d * 8 + x] = b2f((ushort)qv[x]);
    }
  }

  float m = -1e30f, lsum = 0.f;
  float acc0 = 0.f, acc1 = 0.f, acc2 = 0.f, acc3 = 0.f;
  int beg = offs[i], end = offs[i + 1];

  for (int base = beg; base < end; base += CH) {
    int cnt = min(CH, end - base);
    int cnt_pad = (cnt + 7) & ~7;  // >= 8 always
    {
      bool valid = l < cnt;
      int2 te = valid ? ews[base + l] : make_int2(i, 0);
      s_tgt[w][l] = te.x;
      s_w[w][l] = valid ? __int_as_float(te.y) : 0.f;
    }
    wave_lds_sync();

    // ---- score phase: depth-2 pipelined sections of 8 edges, fp8 K ----
    float s_local[8];
#pragma unroll
    for (int it = 0; it < 8; ++it) s_local[it] = -1e30f;

    intx4 kc[2], kn[2];
    {
      const intx4* p = reinterpret_cast<const intx4*>(
          Kb8 + (size_t)s_tgt[w][e8] * 256 + h * 32);
      kc[0] = p[0]; kc[1] = p[1];
    }
    if (8 < cnt_pad) {
      const intx4* p = reinterpret_cast<const intx4*>(
          Kb8 + (size_t)s_tgt[w][8 + e8] * 256 + h * 32);
      kn[0] = p[0]; kn[1] = p[1];
    }
    float cmax = -1e30f;
#pragma unroll
    for (int it = 0; it < 8; ++it) {
      if (it * 8 >= cnt_pad) break;  // wave-uniform
      float dot = 0.f;
#pragma unroll
      for (int c = 0; c < 2; ++c)
#pragma unroll
        for (int e = 0; e < 4; ++e) {
          floatx2 lo = __builtin_amdgcn_cvt_pk_f32_fp8(kc[c][e], false);
          floatx2 hi = __builtin_amdgcn_cvt_pk_f32_fp8(kc[c][e], true);
          int b0 = c * 16 + e * 4;
          dot += qf[b0] * lo[0] + qf[b0 + 1] * lo[1] + qf[b0 + 2] * hi[0] + qf[b0 + 3] * hi[1];
        }
      int j = it * 8 + e8;
      float s = (j < cnt) ? dot * scale + s_w[w][j] * we : -1e30f;
      s_local[it] = s;
      cmax = fmaxf(cmax, s);
      kc[0] = kn[0]; kc[1] = kn[1];
      if ((it + 2) * 8 < cnt_pad) {
        const intx4* p = reinterpret_cast<const intx4*>(
            Kb8 + (size_t)s_tgt[w][(it + 2) * 8 + e8] * 256 + h * 32);
        kn[0] = p[0]; kn[1] = p[1];
      }
    }
    cmax = fmaxf(cmax, __shfl_xor(cmax, 8));
    cmax = fmaxf(cmax, __shfl_xor(cmax, 16));
    cmax = fmaxf(cmax, __shfl_xor(cmax, 32));
    float newm = fmaxf(m, cmax);
    float f = __expf(m - newm);
    float psum = 0.f;
#pragma unroll
    for (int it = 0; it < 8; ++it) {
      if (it * 8 >= cnt_pad) break;
      int j = it * 8 + e8;
      float p = __expf(s_local[it] - newm);
      s_p[w][j][h] = p;
      psum += p;
    }
    psum += __shfl_xor(psum, 8);
    psum += __shfl_xor(psum, 16);
    psum += __shfl_xor(psum, 32);
    lsum = lsum * f + psum;
    m = newm;
    float f_acc = __shfl(f, hacc);
    acc0 *= f_acc; acc1 *= f_acc; acc2 *= f_acc; acc3 *= f_acc;
    wave_lds_sync();

    // ---- PV phase: 8-edge load batches, fp8 V (4B/lane), HW decode ----
#pragma unroll
    for (int g = 0; g < 8; ++g) {
      if (g * 8 >= cnt_pad) break;
      float pv[8];
      int vv[8];
#pragma unroll
      for (int k = 0; k < 8; ++k) {
        int j = g * 8 + k;
        pv[k] = s_p[w][j][hacc];
        vv[k] = *reinterpret_cast<const int*>(
            Vb8 + (size_t)s_tgt[w][j] * 256 + l * 4);
      }
#pragma unroll
      for (int k = 0; k < 8; ++k) {
        floatx2 lo = __builtin_amdgcn_cvt_pk_f32_fp8(vv[k], false);
        floatx2 hi = __builtin_amdgcn_cvt_pk_f32_fp8(vv[k], true);
        acc0 += pv[k] * lo[0];
        acc1 += pv[k] * lo[1];
        acc2 += pv[k] * hi[0];
        acc3 += pv[k] * hi[1];
      }
    }
    wave_lds_sync();
  }
  float lsum_acc = __shfl(lsum, hacc);
  float rinv = (lsum_acc > 0.f) ? 1.f / lsum_acc : 0.f;
  ushort4 o = make_ushort4(f2b(acc0 * rinv), f2b(acc1 * rinv),
                           f2b(acc2 * rinv), f2b(acc3 * rinv));
  *reinterpret_cast<ushort4*>(AGGb + (size_t)i * 256 + l * 4) = o;
}

// ------- output GEMM (LDS-staged, BM=64 BN=256) + residual + LayerNorm ------
__global__ __launch_bounds__(256) void out_ln(
    const ushort* __restrict__ AGGb, const ushort* __restrict__ Wot,
    const float* __restrict__ X, const float* __restrict__ g, const float* __restrict__ bb,
    float* __restrict__ out, int N) {
  __shared__ ushort sA[64 * 64];
  __shared__ ushort sB[256 * 64];
  char* cA = (char*)sA;
  char* cB = (char*)sB;
  int t = threadIdx.x;
  int lane = t & 63, w = t >> 6;
  int row0 = blockIdx.x * 64;
  int lr = lane & 15, kg = lane >> 4;
  f32x4 acc[16] = {};
  for (int k0 = 0; k0 < 256; k0 += 64) {
#pragma unroll
    for (int it = 0; it < 2; ++it) {
      int slot = t + it * 256;
      int row = slot >> 3, kc = slot & 7;
      int grow = min(row0 + row, N - 1);
      short8 va = *reinterpret_cast<const short8*>(AGGb + (size_t)grow * 256 + k0 + kc * 8);
      *reinterpret_cast<short8*>(cA + ((row * 128 + kc * 16) ^ ((row & 7) << 4))) = va;
    }
#pragma unroll
    for (int it = 0; it < 8; ++it) {
      int slot = t + it * 256;
      int col = slot >> 3, kc = slot & 7;
      short8 vb = *reinterpret_cast<const short8*>(Wot + (size_t)col * 256 + k0 + kc * 8);
      *reinterpret_cast<short8*>(cB + ((col * 128 + kc * 16) ^ ((col & 7) << 4))) = vb;
    }
    __syncthreads();
#pragma unroll
    for (int ks = 0; ks < 2; ++ks) {
      int arow = w * 16 + lr;
      short8 a = *reinterpret_cast<const short8*>(
          cA + ((arow * 128 + ks * 64 + kg * 16) ^ ((arow & 7) << 4)));
#pragma unroll
      for (int fc = 0; fc < 16; ++fc) {
        int col = fc * 16 + lr;
        short8 b = *reinterpret_cast<const short8*>(
            cB + ((col * 128 + ks * 64 + kg * 16) ^ ((col & 7) << 4)));
        acc[fc] = __builtin_amdgcn_mfma_f32_16x16x32_bf16(a, b, acc[fc], 0, 0, 0);
      }
    }
    __syncthreads();
  }
  float g16[16], b16[16];
#pragma unroll
  for (int fc = 0; fc < 16; ++fc) {
    g16[fc] = g[fc * 16 + lr];
    b16[fc] = bb[fc * 16 + lr];
  }
#pragma unroll
  for (int r = 0; r < 4; ++r) {
    int rowl = kg * 4 + r;
    int grow = row0 + w * 16 + rowl;
    int growc = min(grow, N - 1);
    float xv[16];
    float s = 0.f, ss = 0.f;
#pragma unroll
    for (int fc = 0; fc < 16; ++fc) {
      float v = acc[fc][r] + X[(size_t)growc * 256 + fc * 16 + lr];
      xv[fc] = v;
      s += v;
      ss += v * v;
    }
    s += __shfl_xor(s, 1);  ss += __shfl_xor(ss, 1);
    s += __shfl_xor(s, 2);  ss += __shfl_xor(ss, 2);
    s += __shfl_xor(s, 4);  ss += __shfl_xor(ss, 4);
    s += __shfl_xor(s, 8);  ss += __shfl_xor(ss, 8);
    float mu = s * (1.f / 256.f);
    float var = ss * (1.f / 256.f) - mu * mu;
    float rs = rsqrtf(var + 1e-5f);
    if (grow < N) {
#pragma unroll
      for (int fc = 0; fc < 16; ++fc)
        out[(size_t)grow * 256 + fc * 16 + lr] = (xv[fc] - mu) * rs * g16[fc] + b16[fc];
    }
  }
}

extern "C" void kernel_launch(void* const* d_in, const int* in_sizes, int n_in,
                              void* d_out, int out_size, void* d_ws, size_t ws_size,
                              hipStream_t stream) {
  const float* X  = (const float*)d_in[0];
  const int* eidx = (const int*)d_in[1];
  const float* ew = (const float*)d_in[2];
  const float* Wq = (const float*)d_in[3];
  const float* Wk = (const float*)d_in[4];
  const float* Wv = (const float*)d_in[5];
  const float* We = (const float*)d_in[6];
  const float* Wo = (const float*)d_in[7];
  const float* g  = (const float*)d_in[8];
  const float* b  = (const float*)d_in[9];
  int N = in_sizes[0] / 256;
  int E = in_sizes[1] / 2;
  const int* src = eidx;
  const int* tgt = eidx + E;
  float* out = (float*)d_out;

  char* w = (char*)d_ws;
  ushort* Xb   = (ushort*)w;        w += (size_t)N * 256 * 2;
  ushort* Wt   = (ushort*)w;        w += (size_t)1024 * 256 * 2;
  ushort* Qb   = (ushort*)w;        w += (size_t)N * 256 * 2;
  unsigned char* Kb8 = (unsigned char*)w;  w += (size_t)N * 256;
  unsigned char* Vb8 = (unsigned char*)w;  w += (size_t)N * 256;
  ushort* AGGb = (ushort*)w;        w += (size_t)N * 256 * 2;
  int* counts  = (int*)w;           w += (size_t)N * 4;
  int* offs    = (int*)w;           w += (size_t)(N + 1) * 4;
  int* cursor  = (int*)w;           w += (size_t)N * 4;
  int2* ews    = (int2*)w;          w += (size_t)E * 8;
  const ushort* Wot = Wt + (size_t)768 * 256;

  int nX = N * 256;
  int nxb = (nX / 8 + 255) / 256;
  int nzero = (N + 255) / 256;
  pre_kernel<<<nxb + 256 + nzero, 256, 0, stream>>>(X, Xb, nX, Wq, Wk, Wv, Wo, Wt, counts, N, nxb);

  int ngemm = ((N + 127) / 128) * 6;
  int nhist = (E + 255) / 256;
  gemm_hist<<<ngemm + nhist, 256, 0, stream>>>(Xb, Wt, Qb, Kb8, Vb8, src, counts, N, E, ngemm);

  scan_kernel<<<1, 1024, 0, stream>>>(counts, offs, cursor, N);
  scatter_kernel<<<(E + 255) / 256, 256, 0, stream>>>(src, tgt, ew, cursor, ews, E);
  attn_kernel<<<(N + 3) / 4, 256, 0, stream>>>(Qb, Kb8, Vb8, offs, ews, We, AGGb, N);
  out_ln<<<(N + 63) / 64, 256, 0, stream>>>(AGGb, Wot, X, g, b, out, N);
}